// Round 1
// baseline (223.875 us; speedup 1.0000x reference)
//
#include <hip/hip_runtime.h>

typedef unsigned short u16;
typedef __attribute__((ext_vector_type(4))) unsigned short u16x4;
typedef __attribute__((ext_vector_type(8))) unsigned short u16x8;
typedef __attribute__((ext_vector_type(8))) short s16x8;
typedef __attribute__((ext_vector_type(4))) float f32x4;

#define LOG2E 1.4426950408889634f

__device__ __forceinline__ u16 f2bf(float f) {
    return __builtin_bit_cast(unsigned short, static_cast<__bf16>(f));
}

__device__ __forceinline__ float fexp2(float x) {
#if __has_builtin(__builtin_amdgcn_exp2f)
    return __builtin_amdgcn_exp2f(x);
#else
    return exp2f(x);
#endif
}

__device__ __forceinline__ s16x8 ld_frag(const u16* p) {
    return __builtin_bit_cast(s16x8, *reinterpret_cast<const u16x8*>(p));
}

__device__ __forceinline__ f32x4 mfma16(s16x8 a, s16x8 b, f32x4 c) {
    return __builtin_amdgcn_mfma_f32_16x16x32_bf16(a, b, c, 0, 0, 0);
}

// async global->LDS, 16B per lane; LDS dest = wave-uniform base + lane*16
__device__ __forceinline__ void async16(const u16* g, u16* lds) {
    __builtin_amdgcn_global_load_lds(
        (__attribute__((address_space(1))) void*)const_cast<u16*>(g),
        (__attribute__((address_space(3))) void*)lds, 16, 0, 0);
}

// ---------------- elementwise f32 -> bf16 ----------------
__global__ __launch_bounds__(256) void cvt_bf16_kernel(const float* __restrict__ in,
                                                       u16* __restrict__ out, int n8) {
    int i = blockIdx.x * 256 + threadIdx.x;
    if (i >= n8) return;
    const f32x4* p = (const f32x4*)in + ((size_t)i << 1);
    f32x4 a = p[0], c = p[1];
    u16x8 v;
    v[0] = f2bf(a[0]); v[1] = f2bf(a[1]); v[2] = f2bf(a[2]); v[3] = f2bf(a[3]);
    v[4] = f2bf(c[0]); v[5] = f2bf(c[1]); v[6] = f2bf(c[2]); v[7] = f2bf(c[3]);
    *((u16x8*)out + i) = v;
}

// ---------------- weight transpose+convert: W[K][512] f32 -> Wt[512][K] bf16 ----------------
__global__ __launch_bounds__(256) void wtrans_kernel(const float* __restrict__ W,
                                                     u16* __restrict__ Wt, int Kd, float scale) {
    __shared__ float t[32][33];
    const int k0 = blockIdx.x << 5, n0 = blockIdx.y << 5;
    const int tx = threadIdx.x, ty = threadIdx.y;
#pragma unroll
    for (int i = 0; i < 32; i += 8)
        t[ty + i][tx] = W[(size_t)(k0 + ty + i) * 512 + n0 + tx] * scale;
    __syncthreads();
#pragma unroll
    for (int i = 0; i < 32; i += 8)
        Wt[(size_t)(n0 + ty + i) * Kd + k0 + tx] = f2bf(t[tx][ty + i]);
}

// ---------------- V transpose: Vb[b*4096+m][h*64+d] -> Vt[bh][d][m] ----------------
__global__ __launch_bounds__(256) void vtrans_kernel(const u16* __restrict__ Vb,
                                                     u16* __restrict__ Vt) {
    __shared__ u16 t[64][72];
    const int bh = blockIdx.y, m0 = blockIdx.x << 6;
    const int b = bh >> 3, h = bh & 7;
    const int tid = threadIdx.x;
#pragma unroll
    for (int i = 0; i < 2; i++) {
        int f = tid + i * 256, r = f >> 3, sg = f & 7;
        u16x8 v = *(const u16x8*)(Vb + (size_t)(b * 4096 + m0 + r) * 512 + (h << 6) + (sg << 3));
        *(u16x8*)&t[r][sg << 3] = v;
    }
    __syncthreads();
#pragma unroll
    for (int i = 0; i < 2; i++) {
        int f = tid + i * 256, dr = f >> 3, sg = f & 7;
        u16x8 v;
#pragma unroll
        for (int j = 0; j < 8; j++) v[j] = t[(sg << 3) + j][dr];
        *(u16x8*)(Vt + (size_t)bh * 262144 + (size_t)dr * 4096 + m0 + (sg << 3)) = v;
    }
}

// ---------------- 128x128 bf16 GEMM body: C[M][512] = A[M][K] @ Bt[512][K]^T ----------------
template <bool BF16OUT>
__device__ __forceinline__ void gemm_body(const u16* __restrict__ A, const u16* __restrict__ Bt,
                                          void* __restrict__ Cv, const float* __restrict__ bias,
                                          int K) {
    __shared__ u16 Ab[2][128 * 64];
    __shared__ u16 Bb[2][128 * 64];
    const int tid = threadIdx.x;
    const int w = tid >> 6, l = tid & 63;
    const int lg = l >> 4, lq = l & 15;
    const int wm = w >> 1, wn = w & 1;
    const int bm = blockIdx.y, bn = blockIdx.x;
    const int KT = K >> 6;

    f32x4 acc[4][4];
#pragma unroll
    for (int i = 0; i < 4; i++)
#pragma unroll
        for (int j = 0; j < 4; j++) acc[i][j] = (f32x4){0.f, 0.f, 0.f, 0.f};

    const u16* Ag0 = A + (size_t)bm * 128 * K;
    const u16* Bg0 = Bt + (size_t)bn * 128 * K;
    const int srow = l >> 3, scol = (l & 7) << 3;

    auto stage = [&](int kt, int buf) {
#pragma unroll
        for (int i = 0; i < 4; i++) {
            const int c = (w << 2) + i;           // chunk 0..15 (8 rows each)
            const int row = (c << 3) + srow;
            async16(Ag0 + (size_t)row * K + kt * 64 + scol, &Ab[buf][c << 9]);
            async16(Bg0 + (size_t)row * K + kt * 64 + scol, &Bb[buf][c << 9]);
        }
    };

    stage(0, 0);
    for (int kt = 0; kt < KT; ++kt) {
        __syncthreads();  // drains vmcnt -> stage(kt) complete; syncs waves
        if (kt + 1 < KT) stage(kt + 1, (kt + 1) & 1);
        const u16* As = Ab[kt & 1];
        const u16* Bs = Bb[kt & 1];
#pragma unroll
        for (int s = 0; s < 2; s++) {
            s16x8 af[4], bfr[4];
#pragma unroll
            for (int mt = 0; mt < 4; mt++)
                af[mt] = ld_frag(As + ((wm << 6) + (mt << 4) + lq) * 64 + (s << 5) + (lg << 3));
#pragma unroll
            for (int nt = 0; nt < 4; nt++)
                bfr[nt] = ld_frag(Bs + ((wn << 6) + (nt << 4) + lq) * 64 + (s << 5) + (lg << 3));
#pragma unroll
            for (int mt = 0; mt < 4; mt++)
#pragma unroll
                for (int nt = 0; nt < 4; nt++)
                    acc[mt][nt] = mfma16(af[mt], bfr[nt], acc[mt][nt]);
        }
    }
    const int row0 = bm * 128 + (wm << 6);
    const int col0 = bn * 128 + (wn << 6);
    if (BF16OUT) {
        u16* C = (u16*)Cv;
#pragma unroll
        for (int mt = 0; mt < 4; mt++)
#pragma unroll
            for (int nt = 0; nt < 4; nt++)
#pragma unroll
                for (int r = 0; r < 4; r++)
                    C[(size_t)(row0 + (mt << 4) + (lg << 2) + r) * 512 + col0 + (nt << 4) + lq] =
                        f2bf(acc[mt][nt][r]);
    } else {
        float* C = (float*)Cv;
        float bv[4];
#pragma unroll
        for (int nt = 0; nt < 4; nt++) bv[nt] = bias[col0 + (nt << 4) + lq];
#pragma unroll
        for (int mt = 0; mt < 4; mt++)
#pragma unroll
            for (int nt = 0; nt < 4; nt++)
#pragma unroll
                for (int r = 0; r < 4; r++)
                    C[(size_t)(row0 + (mt << 4) + (lg << 2) + r) * 512 + col0 + (nt << 4) + lq] =
                        acc[mt][nt][r] + bv[nt];
    }
}

// fused QKV projection: z=0 -> Q (K=512), z=1 -> K (768), z=2 -> V (768)
__global__ __launch_bounds__(256, 2) void proj_gemm_kernel(
    const u16* __restrict__ xb, const u16* __restrict__ cb, const u16* __restrict__ Wqt,
    const u16* __restrict__ Wkt, const u16* __restrict__ Wvt, u16* __restrict__ Qb,
    u16* __restrict__ Kb, u16* __restrict__ Vb) {
    const int z = blockIdx.z;
    if (z == 0)
        gemm_body<true>(xb, Wqt, Qb, nullptr, 512);
    else if (z == 1)
        gemm_body<true>(cb, Wkt, Kb, nullptr, 768);
    else
        gemm_body<true>(cb, Wvt, Vb, nullptr, 768);
}

__global__ __launch_bounds__(256, 2) void out_gemm_kernel(const u16* __restrict__ Ob,
                                                          const u16* __restrict__ Wot,
                                                          float* __restrict__ out,
                                                          const float* __restrict__ bias) {
    gemm_body<false>(Ob, Wot, out, bias, 512);
}

// ---------------- flash attention ----------------
// grid (64 q-tiles, 16 bh); block 256 (4 waves x 16 q-rows). KVBLK=64.
// Swapped QK^T: S^T = mfma(K_frag, Q_frag) -> lane holds S[q=l&15][kv=(l>>4)*4+r].
// Scores already in exp2 domain (SCALE*log2e folded into Wk).
__global__ __launch_bounds__(256) void attn_kernel(const u16* __restrict__ Qb,
                                                   const u16* __restrict__ Kb,
                                                   const u16* __restrict__ Vt,
                                                   u16* __restrict__ Ob) {
    __shared__ u16 Kl[64][72];       // [kv][d], pad 72 to break bank conflicts
    __shared__ u16 Vl[64][72];       // [d][kv] (V^T tile)
    __shared__ u16 Pl[4][16][72];    // per-wave P buffer [q][kv]
    const int tid = threadIdx.x;
    const int w = tid >> 6, l = tid & 63;
    const int lg = l >> 4, lq = l & 15;
    const int bh = blockIdx.y, b = bh >> 3, h = bh & 7;
    const int q0 = blockIdx.x << 6;

    // Q fragments (B operand): lane holds Q[q=lq][d = lg*8 + 32s], hoisted
    const u16* Qp = Qb + (size_t)(b * 4096 + q0 + (w << 4) + lq) * 512 + (h << 6) + (lg << 3);
    s16x8 qf0 = ld_frag(Qp);
    s16x8 qf1 = ld_frag(Qp + 32);

    const u16* Kg0 = Kb + (size_t)b * 4096 * 512 + (h << 6);
    const u16* Vg0 = Vt + (size_t)bh * 262144;

    f32x4 o[4];
#pragma unroll
    for (int dt = 0; dt < 4; dt++) o[dt] = (f32x4){0.f, 0.f, 0.f, 0.f};
    float m_st = -3.0e38f, l_st = 0.f;

    const int srow = tid >> 3, scol = (tid & 7) << 3;  // staging: 32 rows x 8 segs per pass

    for (int kv0 = 0; kv0 < 4096; kv0 += 64) {
        __syncthreads();  // all waves done reading previous K/V tiles
        const u16* Kg = Kg0 + (size_t)kv0 * 512;
        const u16* Vg = Vg0 + kv0;
        u16x8 k_a = *(const u16x8*)(Kg + (size_t)srow * 512 + scol);
        u16x8 k_b = *(const u16x8*)(Kg + (size_t)(srow + 32) * 512 + scol);
        u16x8 v_a = *(const u16x8*)(Vg + (size_t)srow * 4096 + scol);
        u16x8 v_b = *(const u16x8*)(Vg + (size_t)(srow + 32) * 4096 + scol);
        *(u16x8*)&Kl[srow][scol] = k_a;
        *(u16x8*)&Kl[srow + 32][scol] = k_b;
        *(u16x8*)&Vl[srow][scol] = v_a;
        *(u16x8*)&Vl[srow + 32][scol] = v_b;
        __syncthreads();

        // S^T tiles: s[t] = K_tile(16kv x 64d) . Q^T
        f32x4 s[4];
#pragma unroll
        for (int t = 0; t < 4; t++) {
            s[t] = (f32x4){0.f, 0.f, 0.f, 0.f};
            s16x8 kf0 = ld_frag(&Kl[(t << 4) + lq][lg << 3]);
            s16x8 kf1 = ld_frag(&Kl[(t << 4) + lq][32 + (lg << 3)]);
            s[t] = mfma16(kf0, qf0, s[t]);
            s[t] = mfma16(kf1, qf1, s[t]);
        }
        // online softmax (exp2 domain); lane owns row q=lq (replicated x4 groups)
        float pm = s[0][0];
#pragma unroll
        for (int t = 0; t < 4; t++)
#pragma unroll
            for (int r = 0; r < 4; r++) pm = fmaxf(pm, s[t][r]);
        pm = fmaxf(pm, __shfl_xor(pm, 16));
        pm = fmaxf(pm, __shfl_xor(pm, 32));
        const float mn = fmaxf(m_st, pm);
        const float alpha = fexp2(m_st - mn);
        m_st = mn;
        float rs = 0.f;
#pragma unroll
        for (int t = 0; t < 4; t++)
#pragma unroll
            for (int r = 0; r < 4; r++) {
                float p = fexp2(s[t][r] - mn);
                s[t][r] = p;
                rs += p;
            }
        rs += __shfl_xor(rs, 16);
        rs += __shfl_xor(rs, 32);
        l_st = l_st * alpha + rs;
        // P -> LDS in A-fragment layout [q][kv]
#pragma unroll
        for (int t = 0; t < 4; t++) {
            u16x4 pk;
            pk[0] = f2bf(s[t][0]); pk[1] = f2bf(s[t][1]);
            pk[2] = f2bf(s[t][2]); pk[3] = f2bf(s[t][3]);
            *(u16x4*)&Pl[w][lq][(t << 4) + (lg << 2)] = pk;
        }
        // rescale O: lane's O rows are q' = lg*4+r; alpha lives in lane q'
        float ar0 = __shfl(alpha, (lg << 2) + 0);
        float ar1 = __shfl(alpha, (lg << 2) + 1);
        float ar2 = __shfl(alpha, (lg << 2) + 2);
        float ar3 = __shfl(alpha, (lg << 2) + 3);
#pragma unroll
        for (int dt = 0; dt < 4; dt++) {
            o[dt][0] *= ar0; o[dt][1] *= ar1; o[dt][2] *= ar2; o[dt][3] *= ar3;
        }
        // PV: O += P(16q x 64kv) @ V(64kv x 64d)
#pragma unroll
        for (int ks = 0; ks < 2; ks++) {
            s16x8 pf = ld_frag(&Pl[w][lq][(ks << 5) + (lg << 3)]);
#pragma unroll
            for (int dt = 0; dt < 4; dt++) {
                s16x8 vf = ld_frag(&Vl[(dt << 4) + lq][(ks << 5) + (lg << 3)]);
                o[dt] = mfma16(pf, vf, o[dt]);
            }
        }
    }
    float li[4];
#pragma unroll
    for (int r = 0; r < 4; r++) li[r] = 1.f / __shfl(l_st, (lg << 2) + r);
    u16* Op = Ob + (size_t)(b * 4096 + q0 + (w << 4)) * 512 + (h << 6);
#pragma unroll
    for (int dt = 0; dt < 4; dt++)
#pragma unroll
        for (int r = 0; r < 4; r++)
            Op[(size_t)((lg << 2) + r) * 512 + (dt << 4) + lq] = f2bf(o[dt][r] * li[r]);
}

extern "C" void kernel_launch(void* const* d_in, const int* in_sizes, int n_in, void* d_out,
                              int out_size, void* d_ws, size_t ws_size, hipStream_t stream) {
    const float* x = (const float*)d_in[0];    // (2,4096,512)
    const float* ctx = (const float*)d_in[1];  // (2,4096,768)
    const float* Wq = (const float*)d_in[2];   // (512,512)
    const float* Wk = (const float*)d_in[3];   // (768,512)
    const float* Wv = (const float*)d_in[4];   // (768,512)
    const float* Wo = (const float*)d_in[5];   // (512,512)
    const float* bo = (const float*)d_in[6];   // (512,)
    float* out = (float*)d_out;

    char* ws = (char*)d_ws;
    u16* xb  = (u16*)(ws);              // 8,388,608 B
    u16* cb  = (u16*)(ws + 8388608);    // 12,582,912 B
    u16* Wqt = (u16*)(ws + 20971520);   // 524,288 B
    u16* Wkt = (u16*)(ws + 21495808);   // 786,432 B
    u16* Wvt = (u16*)(ws + 22282240);   // 786,432 B
    u16* Wot = (u16*)(ws + 23068672);   // 524,288 B
    u16* Qb  = (u16*)(ws + 23592960);   // 8,388,608 B
    u16* Kb  = (u16*)(ws + 31981568);   // 8,388,608 B
    u16* Vb  = (u16*)(ws + 40370176);   // 8,388,608 B
    u16* Vt  = (u16*)(ws + 48758784);   // 8,388,608 B
    u16* Ob  = (u16*)(ws + 57147392);   // 8,388,608 B  (total 65,536,000 B)

    // 1. bf16 conversions
    cvt_bf16_kernel<<<dim3(2048), dim3(256), 0, stream>>>(x, xb, 4194304 / 8);
    cvt_bf16_kernel<<<dim3(3072), dim3(256), 0, stream>>>(ctx, cb, 6291456 / 8);
    // 2. weight transposes (fold SCALE*log2e into Wk so softmax runs in exp2 domain)
    wtrans_kernel<<<dim3(16, 16), dim3(32, 8), 0, stream>>>(Wq, Wqt, 512, 1.0f);
    wtrans_kernel<<<dim3(24, 16), dim3(32, 8), 0, stream>>>(Wk, Wkt, 768, 0.125f * LOG2E);
    wtrans_kernel<<<dim3(24, 16), dim3(32, 8), 0, stream>>>(Wv, Wvt, 768, 1.0f);
    wtrans_kernel<<<dim3(16, 16), dim3(32, 8), 0, stream>>>(Wo, Wot, 512, 1.0f);
    // 3. fused QKV projections
    proj_gemm_kernel<<<dim3(4, 64, 3), dim3(256), 0, stream>>>(xb, cb, Wqt, Wkt, Wvt, Qb, Kb, Vb);
    // 4. V transpose for PV B-operand
    vtrans_kernel<<<dim3(64, 16), dim3(256), 0, stream>>>(Vb, Vt);
    // 5. flash attention
    attn_kernel<<<dim3(64, 16), dim3(256), 0, stream>>>(Qb, Kb, Vt, Ob);
    // 6. output projection + bias (f32 out)
    out_gemm_kernel<<<dim3(4, 64), dim3(256), 0, stream>>>(Ob, Wot, out, bo);
}

// Round 2
// 180.775 us; speedup vs baseline: 1.2384x; 1.2384x over previous
//
#include <hip/hip_runtime.h>

typedef unsigned short u16;
typedef __attribute__((ext_vector_type(4))) unsigned short u16x4;
typedef __attribute__((ext_vector_type(8))) unsigned short u16x8;
typedef __attribute__((ext_vector_type(8))) short s16x8;
typedef __attribute__((ext_vector_type(4))) float f32x4;
typedef __attribute__((ext_vector_type(16))) float f32x16;
typedef __attribute__((ext_vector_type(4))) unsigned int u32x4;

#define LOG2E 1.4426950408889634f

__device__ __forceinline__ u16 f2bf(float f) {
    return __builtin_bit_cast(unsigned short, static_cast<__bf16>(f));
}

__device__ __forceinline__ float fexp2(float x) {
#if __has_builtin(__builtin_amdgcn_exp2f)
    return __builtin_amdgcn_exp2f(x);
#else
    return exp2f(x);
#endif
}

__device__ __forceinline__ s16x8 ld_frag(const u16* p) {
    return __builtin_bit_cast(s16x8, *reinterpret_cast<const u16x8*>(p));
}

__device__ __forceinline__ f32x4 mfma16(s16x8 a, s16x8 b, f32x4 c) {
    return __builtin_amdgcn_mfma_f32_16x16x32_bf16(a, b, c, 0, 0, 0);
}

__device__ __forceinline__ f32x16 mfma32(s16x8 a, s16x8 b, f32x16 c) {
    return __builtin_amdgcn_mfma_f32_32x32x16_bf16(a, b, c, 0, 0, 0);
}

__device__ __forceinline__ unsigned cvt_pk_bf16(float lo, float hi2) {
    unsigned r;
    asm("v_cvt_pk_bf16_f32 %0, %1, %2" : "=v"(r) : "v"(lo), "v"(hi2));
    return r;
}

// exchange x's upper-32-lane half with y's lower-32-lane half
__device__ __forceinline__ void plane32_swap(unsigned& x, unsigned& y) {
#if __has_builtin(__builtin_amdgcn_permlane32_swap)
    auto r = __builtin_amdgcn_permlane32_swap(x, y, false, false);
    x = r[0];
    y = r[1];
#else
    asm("v_permlane32_swap_b32 %0, %1" : "+v"(x), "+v"(y));
#endif
}

// async global->LDS, 16B per lane; LDS dest = wave-uniform base + lane*16
__device__ __forceinline__ void async16(const u16* g, u16* lds) {
    __builtin_amdgcn_global_load_lds(
        (__attribute__((address_space(1))) void*)const_cast<u16*>(g),
        (__attribute__((address_space(3))) void*)lds, 16, 0, 0);
}

// ---------------- elementwise f32 -> bf16 ----------------
__global__ __launch_bounds__(256) void cvt_bf16_kernel(const float* __restrict__ in,
                                                       u16* __restrict__ out, int n8) {
    int i = blockIdx.x * 256 + threadIdx.x;
    if (i >= n8) return;
    const f32x4* p = (const f32x4*)in + ((size_t)i << 1);
    f32x4 a = p[0], c = p[1];
    u16x8 v;
    v[0] = f2bf(a[0]); v[1] = f2bf(a[1]); v[2] = f2bf(a[2]); v[3] = f2bf(a[3]);
    v[4] = f2bf(c[0]); v[5] = f2bf(c[1]); v[6] = f2bf(c[2]); v[7] = f2bf(c[3]);
    *((u16x8*)out + i) = v;
}

// ---------------- weight transpose+convert: W[K][512] f32 -> Wt[512][K] bf16 ----------------
__global__ __launch_bounds__(256) void wtrans_kernel(const float* __restrict__ W,
                                                     u16* __restrict__ Wt, int Kd, float scale) {
    __shared__ float t[32][33];
    const int k0 = blockIdx.x << 5, n0 = blockIdx.y << 5;
    const int tx = threadIdx.x, ty = threadIdx.y;
#pragma unroll
    for (int i = 0; i < 32; i += 8)
        t[ty + i][tx] = W[(size_t)(k0 + ty + i) * 512 + n0 + tx] * scale;
    __syncthreads();
#pragma unroll
    for (int i = 0; i < 32; i += 8)
        Wt[(size_t)(n0 + ty + i) * Kd + k0 + tx] = f2bf(t[tx][ty + i]);
}

// ---------------- V transpose: Vb[b*4096+m][h*64+d] -> Vt[bh][d][m] ----------------
__global__ __launch_bounds__(256) void vtrans_kernel(const u16* __restrict__ Vb,
                                                     u16* __restrict__ Vt) {
    __shared__ u16 t[64][72];
    const int bh = blockIdx.y, m0 = blockIdx.x << 6;
    const int b = bh >> 3, h = bh & 7;
    const int tid = threadIdx.x;
#pragma unroll
    for (int i = 0; i < 2; i++) {
        int f = tid + i * 256, r = f >> 3, sg = f & 7;
        u16x8 v = *(const u16x8*)(Vb + (size_t)(b * 4096 + m0 + r) * 512 + (h << 6) + (sg << 3));
        *(u16x8*)&t[r][sg << 3] = v;
    }
    __syncthreads();
#pragma unroll
    for (int i = 0; i < 2; i++) {
        int f = tid + i * 256, dr = f >> 3, sg = f & 7;
        u16x8 v;
#pragma unroll
        for (int j = 0; j < 8; j++) v[j] = t[(sg << 3) + j][dr];
        *(u16x8*)(Vt + (size_t)bh * 262144 + (size_t)dr * 4096 + m0 + (sg << 3)) = v;
    }
}

// ---------------- 128x128 bf16 GEMM body: C[M][512] = A[M][K] @ Bt[512][K]^T ----------------
template <bool BF16OUT>
__device__ __forceinline__ void gemm_body(const u16* __restrict__ A, const u16* __restrict__ Bt,
                                          void* __restrict__ Cv, const float* __restrict__ bias,
                                          int K) {
    __shared__ u16 Ab[2][128 * 64];
    __shared__ u16 Bb[2][128 * 64];
    const int tid = threadIdx.x;
    const int w = tid >> 6, l = tid & 63;
    const int lg = l >> 4, lq = l & 15;
    const int wm = w >> 1, wn = w & 1;
    const int bm = blockIdx.y, bn = blockIdx.x;
    const int KT = K >> 6;

    f32x4 acc[4][4];
#pragma unroll
    for (int i = 0; i < 4; i++)
#pragma unroll
        for (int j = 0; j < 4; j++) acc[i][j] = (f32x4){0.f, 0.f, 0.f, 0.f};

    const u16* Ag0 = A + (size_t)bm * 128 * K;
    const u16* Bg0 = Bt + (size_t)bn * 128 * K;
    const int srow = l >> 3, scol = (l & 7) << 3;

    auto stage = [&](int kt, int buf) {
#pragma unroll
        for (int i = 0; i < 4; i++) {
            const int c = (w << 2) + i;
            const int row = (c << 3) + srow;
            async16(Ag0 + (size_t)row * K + kt * 64 + scol, &Ab[buf][c << 9]);
            async16(Bg0 + (size_t)row * K + kt * 64 + scol, &Bb[buf][c << 9]);
        }
    };

    stage(0, 0);
    for (int kt = 0; kt < KT; ++kt) {
        __syncthreads();
        if (kt + 1 < KT) stage(kt + 1, (kt + 1) & 1);
        const u16* As = Ab[kt & 1];
        const u16* Bs = Bb[kt & 1];
#pragma unroll
        for (int s = 0; s < 2; s++) {
            s16x8 af[4], bfr[4];
#pragma unroll
            for (int mt = 0; mt < 4; mt++)
                af[mt] = ld_frag(As + ((wm << 6) + (mt << 4) + lq) * 64 + (s << 5) + (lg << 3));
#pragma unroll
            for (int nt = 0; nt < 4; nt++)
                bfr[nt] = ld_frag(Bs + ((wn << 6) + (nt << 4) + lq) * 64 + (s << 5) + (lg << 3));
#pragma unroll
            for (int mt = 0; mt < 4; mt++)
#pragma unroll
                for (int nt = 0; nt < 4; nt++)
                    acc[mt][nt] = mfma16(af[mt], bfr[nt], acc[mt][nt]);
        }
    }
    const int row0 = bm * 128 + (wm << 6);
    const int col0 = bn * 128 + (wn << 6);
    if (BF16OUT) {
        u16* C = (u16*)Cv;
#pragma unroll
        for (int mt = 0; mt < 4; mt++)
#pragma unroll
            for (int nt = 0; nt < 4; nt++)
#pragma unroll
                for (int r = 0; r < 4; r++)
                    C[(size_t)(row0 + (mt << 4) + (lg << 2) + r) * 512 + col0 + (nt << 4) + lq] =
                        f2bf(acc[mt][nt][r]);
    } else {
        float* C = (float*)Cv;
        float bv[4];
#pragma unroll
        for (int nt = 0; nt < 4; nt++) bv[nt] = bias[col0 + (nt << 4) + lq];
#pragma unroll
        for (int mt = 0; mt < 4; mt++)
#pragma unroll
            for (int nt = 0; nt < 4; nt++)
#pragma unroll
                for (int r = 0; r < 4; r++)
                    C[(size_t)(row0 + (mt << 4) + (lg << 2) + r) * 512 + col0 + (nt << 4) + lq] =
                        acc[mt][nt][r] + bv[nt];
    }
}

__global__ __launch_bounds__(256, 2) void proj_gemm_kernel(
    const u16* __restrict__ xb, const u16* __restrict__ cb, const u16* __restrict__ Wqt,
    const u16* __restrict__ Wkt, const u16* __restrict__ Wvt, u16* __restrict__ Qb,
    u16* __restrict__ Kb, u16* __restrict__ Vb) {
    const int z = blockIdx.z;
    if (z == 0)
        gemm_body<true>(xb, Wqt, Qb, nullptr, 512);
    else if (z == 1)
        gemm_body<true>(cb, Wkt, Kb, nullptr, 768);
    else
        gemm_body<true>(cb, Wvt, Vb, nullptr, 768);
}

__global__ __launch_bounds__(256, 2) void out_gemm_kernel(const u16* __restrict__ Ob,
                                                          const u16* __restrict__ Wot,
                                                          float* __restrict__ out,
                                                          const float* __restrict__ bias) {
    gemm_body<false>(Ob, Wot, out, bias, 512);
}

// ---------------- flash attention, 32x32 swapped structure ----------------
// grid (32 q-tiles of 128, 16 bh); block 256 = 4 waves x 32 q-rows. KVBLK=64.
// S^T = mfma32(K, Q): lane owns full P-row for q = lane&31 (kv split across hi).
// In-register softmax + cvt_pk/permlane32_swap P->A redistribution (T12).
// K/V staged in XOR-swizzled LDS (seg ^= row&7) -> conflict-balanced b128.
__global__ __launch_bounds__(256, 2) void attn_kernel(const u16* __restrict__ Qb,
                                                      const u16* __restrict__ Kb,
                                                      const u16* __restrict__ Vt,
                                                      u16* __restrict__ Ob) {
    __shared__ u16 Kl[2][64][64];
    __shared__ u16 Vl[2][64][64];
    __shared__ float xBuf[4][32];
    const int tid = threadIdx.x;
    const int w = tid >> 6, l = tid & 63;
    const int lq = l & 31, hi = l >> 5;
    const int bh = blockIdx.y, b = bh >> 3, h = bh & 7;
    const int q0 = (blockIdx.x << 7) + (w << 5);

    // Q B-fragments: qf[s] = Q[q0+lq][d = hi*8 + j + 16s]
    const u16* Qp = Qb + (size_t)(b * 4096 + q0 + lq) * 512 + (h << 6) + (hi << 3);
    s16x8 qf[4];
#pragma unroll
    for (int s = 0; s < 4; s++) qf[s] = ld_frag(Qp + (s << 4));

    const u16* Kg0 = Kb + (size_t)b * 4096 * 512 + (h << 6);
    const u16* Vg0 = Vt + (size_t)bh * 262144;

    const int srow = tid >> 3, sseg = tid & 7;
    const int swcol = (sseg ^ (srow & 7)) << 3;  // swizzled u16 col for staging

    // per-lane swizzled read offsets (u16 units): seg' = (hi+2s) ^ (l&7)
    int offs[4];
    {
        const int clo = (hi ^ (l & 1)) << 3;
        const int d2 = (l >> 1) & 3;
#pragma unroll
        for (int s = 0; s < 4; s++) offs[s] = clo + ((s ^ d2) << 4);
    }

    f32x16 oacc[2];
#pragma unroll
    for (int dt = 0; dt < 2; dt++)
#pragma unroll
        for (int r = 0; r < 16; r++) oacc[dt][r] = 0.f;
    float m_st = -3.0e38f, l_st = 0.f;

    // prologue: stage tile 0 -> buf 0
    {
        u16x8 ka = *(const u16x8*)(Kg0 + (size_t)srow * 512 + sseg * 8);
        u16x8 kc = *(const u16x8*)(Kg0 + (size_t)(srow + 32) * 512 + sseg * 8);
        u16x8 va = *(const u16x8*)(Vg0 + (size_t)srow * 4096 + sseg * 8);
        u16x8 vc = *(const u16x8*)(Vg0 + (size_t)(srow + 32) * 4096 + sseg * 8);
        *(u16x8*)&Kl[0][srow][swcol] = ka;
        *(u16x8*)&Kl[0][srow + 32][swcol] = kc;
        *(u16x8*)&Vl[0][srow][swcol] = va;
        *(u16x8*)&Vl[0][srow + 32][swcol] = vc;
    }

    for (int it = 0; it < 64; ++it) {
        const int buf = it & 1;
        __syncthreads();  // staged tile `it` visible; prev-tile readers done
        // T14: issue next-tile global loads early, write to LDS after PV
        u16x8 ka, kc, va, vc;
        const bool more = it + 1 < 64;
        if (more) {
            const int kv = (it + 1) << 6;
            ka = *(const u16x8*)(Kg0 + (size_t)(kv + srow) * 512 + sseg * 8);
            kc = *(const u16x8*)(Kg0 + (size_t)(kv + srow + 32) * 512 + sseg * 8);
            va = *(const u16x8*)(Vg0 + (size_t)srow * 4096 + kv + sseg * 8);
            vc = *(const u16x8*)(Vg0 + (size_t)(srow + 32) * 4096 + kv + sseg * 8);
        }
        const u16* Kbuf = &Kl[buf][0][0];
        const u16* Vbuf = &Vl[buf][0][0];

        // QK^T: sacc[t][r] = S[q=lq][kv = (r&3)+8*(r>>2)+4*hi + 32t]
        f32x16 sacc[2];
#pragma unroll
        for (int t = 0; t < 2; t++) {
#pragma unroll
            for (int r = 0; r < 16; r++) sacc[t][r] = 0.f;
#pragma unroll
            for (int s = 0; s < 4; s++) {
                s16x8 kf = ld_frag(Kbuf + ((lq + (t << 5)) << 6) + offs[s]);
                sacc[t] = mfma32(kf, qf[s], sacc[t]);
            }
        }

        // online softmax (exp2 domain), row q = lq held by lane pair (l, l+32)
        float pm = sacc[0][0];
#pragma unroll
        for (int t = 0; t < 2; t++)
#pragma unroll
            for (int r = 0; r < 16; r++) pm = fmaxf(pm, sacc[t][r]);
        pm = fmaxf(pm, __shfl_xor(pm, 32));
        const float mn = fmaxf(m_st, pm);
        const float alpha = fexp2(m_st - mn);
        m_st = mn;
        float rs = 0.f;
#pragma unroll
        for (int t = 0; t < 2; t++)
#pragma unroll
            for (int r = 0; r < 16; r++) {
                float p = fexp2(sacc[t][r] - mn);
                sacc[t][r] = p;
                rs += p;
            }
        rs += __shfl_xor(rs, 32);
        l_st = l_st * alpha + rs;

        // alpha broadcast to O-layout via per-wave LDS (q = (r&3)+8u+4hi)
        if (hi == 0) xBuf[w][lq] = alpha;
        asm volatile("s_waitcnt lgkmcnt(0)" ::: "memory");
        __builtin_amdgcn_sched_barrier(0);
        f32x4 ar[4];
#pragma unroll
        for (int u = 0; u < 4; u++) ar[u] = *(const f32x4*)&xBuf[w][(hi << 2) + (u << 3)];
#pragma unroll
        for (int dt = 0; dt < 2; dt++)
#pragma unroll
            for (int r = 0; r < 16; r++) oacc[dt][r] *= ar[r >> 2][r & 3];

        // P -> A fragments: 16 cvt_pk + 8 permlane32_swap (T12)
        s16x8 aw[4];
#pragma unroll
        for (int s = 0; s < 4; s++) {
            const int tt = s >> 1, base2 = (s & 1) << 3;
            unsigned X1 = cvt_pk_bf16(sacc[tt][base2 + 0], sacc[tt][base2 + 1]);
            unsigned Y1 = cvt_pk_bf16(sacc[tt][base2 + 4], sacc[tt][base2 + 5]);
            unsigned X2 = cvt_pk_bf16(sacc[tt][base2 + 2], sacc[tt][base2 + 3]);
            unsigned Y2 = cvt_pk_bf16(sacc[tt][base2 + 6], sacc[tt][base2 + 7]);
            plane32_swap(X1, Y1);
            plane32_swap(X2, Y2);
            u32x4 wv;
            wv[0] = X1; wv[1] = X2; wv[2] = Y1; wv[3] = Y2;
            aw[s] = __builtin_bit_cast(s16x8, wv);
        }

        // PV: O[q][d] += P[q][kv] @ V[kv][d], V frags from Vl[d][kv]
#pragma unroll
        for (int s = 0; s < 4; s++)
#pragma unroll
            for (int dt = 0; dt < 2; dt++) {
                s16x8 vf = ld_frag(Vbuf + ((lq + (dt << 5)) << 6) + offs[s]);
                oacc[dt] = mfma32(aw[s], vf, oacc[dt]);
            }

        // late LDS write of prefetched tile (vmcnt auto-inserted on reg use)
        if (more) {
            const int nb = buf ^ 1;
            *(u16x8*)&Kl[nb][srow][swcol] = ka;
            *(u16x8*)&Kl[nb][srow + 32][swcol] = kc;
            *(u16x8*)&Vl[nb][srow][swcol] = va;
            *(u16x8*)&Vl[nb][srow + 32][swcol] = vc;
        }
    }

    // epilogue: 1/l broadcast to O-layout, normalize, store
    if (hi == 0) xBuf[w][lq] = 1.f / l_st;
    asm volatile("s_waitcnt lgkmcnt(0)" ::: "memory");
    __builtin_amdgcn_sched_barrier(0);
    f32x4 lr[4];
#pragma unroll
    for (int u = 0; u < 4; u++) lr[u] = *(const f32x4*)&xBuf[w][(hi << 2) + (u << 3)];
    u16* Op = Ob + (size_t)(b * 4096 + q0) * 512 + (h << 6);
#pragma unroll
    for (int dt = 0; dt < 2; dt++)
#pragma unroll
        for (int r = 0; r < 16; r++) {
            const int q = (r & 3) + ((r >> 2) << 3) + (hi << 2);
            Op[(size_t)q * 512 + lq + (dt << 5)] = f2bf(oacc[dt][r] * lr[r >> 2][r & 3]);
        }
}

extern "C" void kernel_launch(void* const* d_in, const int* in_sizes, int n_in, void* d_out,
                              int out_size, void* d_ws, size_t ws_size, hipStream_t stream) {
    const float* x = (const float*)d_in[0];    // (2,4096,512)
    const float* ctx = (const float*)d_in[1];  // (2,4096,768)
    const float* Wq = (const float*)d_in[2];   // (512,512)
    const float* Wk = (const float*)d_in[3];   // (768,512)
    const float* Wv = (const float*)d_in[4];   // (768,512)
    const float* Wo = (const float*)d_in[5];   // (512,512)
    const float* bo = (const float*)d_in[6];   // (512,)
    float* out = (float*)d_out;

    char* ws = (char*)d_ws;
    u16* xb  = (u16*)(ws);
    u16* cb  = (u16*)(ws + 8388608);
    u16* Wqt = (u16*)(ws + 20971520);
    u16* Wkt = (u16*)(ws + 21495808);
    u16* Wvt = (u16*)(ws + 22282240);
    u16* Wot = (u16*)(ws + 23068672);
    u16* Qb  = (u16*)(ws + 23592960);
    u16* Kb  = (u16*)(ws + 31981568);
    u16* Vb  = (u16*)(ws + 40370176);
    u16* Vt  = (u16*)(ws + 48758784);
    u16* Ob  = (u16*)(ws + 57147392);

    cvt_bf16_kernel<<<dim3(2048), dim3(256), 0, stream>>>(x, xb, 4194304 / 8);
    cvt_bf16_kernel<<<dim3(3072), dim3(256), 0, stream>>>(ctx, cb, 6291456 / 8);
    wtrans_kernel<<<dim3(16, 16), dim3(32, 8), 0, stream>>>(Wq, Wqt, 512, 1.0f);
    wtrans_kernel<<<dim3(24, 16), dim3(32, 8), 0, stream>>>(Wk, Wkt, 768, 0.125f * LOG2E);
    wtrans_kernel<<<dim3(24, 16), dim3(32, 8), 0, stream>>>(Wv, Wvt, 768, 1.0f);
    wtrans_kernel<<<dim3(16, 16), dim3(32, 8), 0, stream>>>(Wo, Wot, 512, 1.0f);
    proj_gemm_kernel<<<dim3(4, 64, 3), dim3(256), 0, stream>>>(xb, cb, Wqt, Wkt, Wvt, Qb, Kb, Vb);
    vtrans_kernel<<<dim3(64, 16), dim3(256), 0, stream>>>(Vb, Vt);
    attn_kernel<<<dim3(32, 16), dim3(256), 0, stream>>>(Qb, Kb, Vt, Ob);
    out_gemm_kernel<<<dim3(4, 64), dim3(256), 0, stream>>>(Ob, Wot, out, bo);
}